// Round 2
// 593.598 us; speedup vs baseline: 1.0447x; 1.0447x over previous
//
#include <hip/hip_runtime.h>
#include <hip/hip_bf16.h>

#define CH    32
#define DIM   128
#define DHW   (128*128*128)
#define NVERT 50000
#define NPAD  50048   /* 782 * 64 */

typedef __attribute__((ext_vector_type(4))) float f32x4;
typedef __attribute__((ext_vector_type(8))) short s16x8;

__device__ __forceinline__ float bf2f(unsigned short h) {
    union { unsigned int u; float f; } v; v.u = ((unsigned int)h) << 16; return v.f;
}
__device__ __forceinline__ unsigned short f2b(float f) {
    union { float f; unsigned int u; } v; v.f = f;
    unsigned int u = v.u;
    unsigned int r = u + 0x7fffu + ((u >> 16) & 1u);   // RTNE
    return (unsigned short)(r >> 16);
}

// ---- kernel 1 (v3): fp32 [C][D][H][W] -> bf16 [D][H][W][C] (FROZEN) ----
__global__ __launch_bounds__(256) void k_transpose(const float* __restrict__ vf,
                                                   unsigned short* __restrict__ vol) {
    const int t  = threadIdx.x;
    const int cq = t & 3;
    const int vo = blockIdx.x * 64 + (t >> 2);       // voxel id
    float v[8];
#pragma unroll
    for (int j = 0; j < 8; ++j) v[j] = vf[(size_t)(cq * 8 + j) * DHW + vo];
    union { uint4 u; unsigned short s[8]; } p;
#pragma unroll
    for (int j = 0; j < 8; ++j) p.s[j] = f2b(v[j]);
    ((uint4*)vol)[vo * 4 + cq] = p.u;
}

// ---- kernel 2a: Wd = w_d2@w_d1 (fp32 -> ws) + folded bias (FROZEN) ----
__global__ __launch_bounds__(1024) void k_fold1(
    const float* __restrict__ w_d1, const float* __restrict__ b_d1,
    const float* __restrict__ w_d2, const float* __restrict__ b_d2,
    const float* __restrict__ w_c1, const float* __restrict__ b_c1,
    const float* __restrict__ w_c2, const float* __restrict__ b_c2,
    const float* __restrict__ conv_w, const float* __restrict__ conv_b,
    float* __restrict__ WdG, float* __restrict__ biasOut)
{
    __shared__ float bd[32];
    const int t = threadIdx.x;
    const int o = t >> 5, cc = t & 31;
    float s1 = 0.f;
    for (int j = 0; j < 32; ++j) s1 += w_d2[o * 32 + j] * w_d1[j * 32 + cc];
    WdG[t] = s1;
    if (t < 32) {
        float s = b_d2[t];
        for (int j = 0; j < 32; ++j) s += w_d2[t * 32 + j] * b_d1[j];
        bd[t] = s;   // diff-branch bias after both layers
    }
    __syncthreads();
    if (t < 32) {    // t = o
        float ba = conv_b[t];
        for (int c = 0; c < 32; ++c) {
            float cs = 0.f;
            for (int k = 0; k < 27; ++k) cs += conv_w[(t * 32 + c) * 27 + k];
            ba += cs * bd[c];
        }
        float bc = b_c2[t];
        for (int j = 0; j < 32; ++j) bc += w_c2[t * 32 + j] * b_c1[j];
        biasOut[t] = ba + bc;
    }
}

// ---- kernel 2b: Et[o][k*32+cc] for one shift k per block (27 blocks) (FROZEN) ----
__global__ __launch_bounds__(1024) void k_fold2(
    const float* __restrict__ w_c1, const float* __restrict__ w_c2,
    const float* __restrict__ conv_w, const float* __restrict__ WdG,
    unsigned short* __restrict__ Et)
{
    const int k = blockIdx.x;
    __shared__ float WdL[1024];
    const int t = threadIdx.x;
    WdL[t] = WdG[t];
    __syncthreads();
    const int o = t >> 5, cc = t & 31;
    float s = 0.f;
    for (int c = 0; c < 32; ++c)
        s += conv_w[(o * 32 + c) * 27 + k] * WdL[c * 32 + cc];
    if (k == 13) {
        float wc = 0.f;
        for (int j = 0; j < 32; ++j) wc += w_c2[o * 32 + j] * w_c1[j * 32 + cc];
        float ms = 0.f;
        for (int c = 0; c < 32; ++c) {
            float cs = 0.f;
            for (int kk = 0; kk < 27; ++kk) cs += conv_w[(o * 32 + c) * 27 + kk];
            ms += cs * WdL[c * 32 + cc];
        }
        s += wc - ms;
    }
    Et[o * 864 + k * 32 + cc] = f2b(s);
}

// ---- kernel 3 (NEW): fused trilinear sample + MFMA GEMM ----
// Wave pair covers 16 vertices; lane (m=lane&15, q=lane>>4) samples vertex
// n0+m, channels [q*8, q*8+8) for shift kk — which IS the MFMA A-fragment
// (k_gemm layout, m89-verified). feats never touches memory. kk split 2-way
// across the pair (0..13 / 14..26) for occupancy: 6256 waves = 24/CU.
__global__ __launch_bounds__(256) void k_fused(const float* __restrict__ verts,
                                               const unsigned short* __restrict__ vol,
                                               const unsigned short* __restrict__ Et,
                                               const float* __restrict__ bias,
                                               float* __restrict__ out) {
    __shared__ float part[2][64][8];                 // odd-wave partial accs (4 KB)
    const int wave = threadIdx.x >> 6, lane = threadIdx.x & 63;
    const int grp  = wave >> 1;                      // vertex group within block
    const int half = wave & 1;                       // kk half
    const int n0 = blockIdx.x * 32 + grp * 16;
    const int m = lane & 15, q = lane >> 4;
    const int nv = min(n0 + m, NVERT - 1);
    const float vx = verts[nv * 3 + 0];
    const float vy = verts[nv * 3 + 1];
    const float vz = verts[nv * 3 + 2];
    f32x4 acc0 = {0.f, 0.f, 0.f, 0.f}, acc1 = {0.f, 0.f, 0.f, 0.f};
    const uint4* v4 = (const uint4*)vol;
    const uint4* B0 = (const uint4*)(Et + m * 864) + q;
    const uint4* B1 = (const uint4*)(Et + (m + 16) * 864) + q;
    const int kk0 = half * 14;                       // 0 or 14
    const int kk1 = kk0 + 14 - half;                 // 14 or 27

    for (int kk = kk0; kk < kk1; ++kk) {
        const float sx = (float)(kk / 9) - 1.0f;
        const float sy = (float)((kk / 3) % 3) - 1.0f;
        const float sz = (float)(kk % 3) - 1.0f;
        float fx = (vx + sx * 0.0625f + 1.0f) * 63.5f;
        float fy = (vy + sy * 0.0625f + 1.0f) * 63.5f;
        float fz = (vz + sz * 0.0625f + 1.0f) * 63.5f;
        fx = fminf(fmaxf(fx, 0.f), 127.f);
        fy = fminf(fmaxf(fy, 0.f), 127.f);
        fz = fminf(fmaxf(fz, 0.f), 127.f);
        const int x0 = (int)floorf(fx); const float wx = fx - (float)x0; const int x1 = min(x0 + 1, 127);
        const int y0 = (int)floorf(fy); const float wy = fy - (float)y0; const int y1 = min(y0 + 1, 127);
        const int z0 = (int)floorf(fz); const float wz = fz - (float)z0; const int z1 = min(z0 + 1, 127);
        const float w0x = 1.f - wx, w0y = 1.f - wy, w0z = 1.f - wz;
        const float w000 = w0z * w0y * w0x, w001 = w0z * w0y * wx;
        const float w010 = w0z * wy * w0x,  w011 = w0z * wy * wx;
        const float w100 = wz * w0y * w0x,  w101 = wz * w0y * wx;
        const float w110 = wz * wy * w0x,   w111 = wz * wy * wx;

        const int zy00 = (z0 * 128 + y0) * 128, zy01 = (z0 * 128 + y1) * 128;
        const int zy10 = (z1 * 128 + y0) * 128, zy11 = (z1 * 128 + y1) * 128;
        union U4 { uint4 u; unsigned short s[8]; };
        U4 g000, g001, g010, g011, g100, g101, g110, g111;
        g000.u = v4[(zy00 + x0) * 4 + q];
        g001.u = v4[(zy00 + x1) * 4 + q];
        g010.u = v4[(zy01 + x0) * 4 + q];
        g011.u = v4[(zy01 + x1) * 4 + q];
        g100.u = v4[(zy10 + x0) * 4 + q];
        g101.u = v4[(zy10 + x1) * 4 + q];
        g110.u = v4[(zy11 + x0) * 4 + q];
        g111.u = v4[(zy11 + x1) * 4 + q];

        union AB { uint4 u; s16x8 v; unsigned short s[8]; };
        AB a, b0, b1;
        b0.u = B0[kk * 4];
        b1.u = B1[kk * 4];
#pragma unroll
        for (int j = 0; j < 8; ++j) {
            float s = bf2f(g000.s[j]) * w000 + bf2f(g001.s[j]) * w001
                    + bf2f(g010.s[j]) * w010 + bf2f(g011.s[j]) * w011
                    + bf2f(g100.s[j]) * w100 + bf2f(g101.s[j]) * w101
                    + bf2f(g110.s[j]) * w110 + bf2f(g111.s[j]) * w111;
            a.s[j] = f2b(s);                         // same RTNE as old feats path
        }
        acc0 = __builtin_amdgcn_mfma_f32_16x16x32_bf16(a.v, b0.v, acc0, 0, 0, 0);
        acc1 = __builtin_amdgcn_mfma_f32_16x16x32_bf16(a.v, b1.v, acc1, 0, 0, 0);
    }

    if (half) {                                      // odd wave: publish partials
#pragma unroll
        for (int r = 0; r < 4; ++r) {
            part[grp][lane][r]     = acc0[r];
            part[grp][lane][4 + r] = acc1[r];
        }
    }
    __syncthreads();
    if (!half) {                                     // even wave: combine + store
        const float bi0 = bias[m], bi1 = bias[m + 16];
#pragma unroll
        for (int r = 0; r < 4; ++r) {
            const int n = n0 + q * 4 + r;            // C/D: col=lane&15, row=q*4+r
            if (n < NVERT) {
                out[n * 32 + m]      = acc0[r] + part[grp][lane][r]     + bi0;
                out[n * 32 + 16 + m] = acc1[r] + part[grp][lane][4 + r] + bi1;
            }
        }
    }
}

extern "C" void kernel_launch(void* const* d_in, const int* in_sizes, int n_in,
                              void* d_out, int out_size, void* d_ws, size_t ws_size,
                              hipStream_t stream) {
    const float* vf     = (const float*)d_in[0];
    const float* verts  = (const float*)d_in[1];
    const float* w_d1   = (const float*)d_in[2];
    const float* b_d1   = (const float*)d_in[3];
    const float* w_d2   = (const float*)d_in[4];
    const float* b_d2   = (const float*)d_in[5];
    const float* w_c1   = (const float*)d_in[6];
    const float* b_c1   = (const float*)d_in[7];
    const float* w_c2   = (const float*)d_in[8];
    const float* b_c2   = (const float*)d_in[9];
    const float* conv_w = (const float*)d_in[10];
    const float* conv_b = (const float*)d_in[11];

    // ws: vol bf16 [DHW][32] | Et bf16 [32][864] | bias f32[32] | WdG f32[1024]
    char* ws = (char*)d_ws;
    unsigned short* vol   = (unsigned short*)ws;                                      // 134217728 B
    unsigned short* Et    = (unsigned short*)(ws + 134217728);                        // 55296 B
    float*          bias  = (float*)(ws + 134217728 + 55296);                         // 128 B
    float*          WdG   = (float*)(ws + 134217728 + 55296 + 128);                   // 4096 B

    k_transpose<<<DHW / 64, 256, 0, stream>>>(vf, vol);
    k_fold1<<<1, 1024, 0, stream>>>(w_d1, b_d1, w_d2, b_d2, w_c1, b_c1,
                                    w_c2, b_c2, conv_w, conv_b, WdG, bias);
    k_fold2<<<27, 1024, 0, stream>>>(w_c1, w_c2, conv_w, WdG, Et);
    k_fused<<<NPAD / 32, 256, 0, stream>>>(verts, vol, Et, bias, (float*)d_out);
}

// Round 3
// 563.805 us; speedup vs baseline: 1.0999x; 1.0528x over previous
//
#include <hip/hip_runtime.h>
#include <hip/hip_bf16.h>

#define CH    32
#define DIM   128
#define DHW   (128*128*128)
#define NVERT 50000
#define NPAD  50048   /* 782 * 64 */
#define NCELL 32768   /* 32^3 Morton cells of 4^3 voxels */

typedef __attribute__((ext_vector_type(4))) float f32x4;
typedef __attribute__((ext_vector_type(8))) short s16x8;

__device__ __forceinline__ float bf2f(unsigned short h) {
    union { unsigned int u; float f; } v; v.u = ((unsigned int)h) << 16; return v.f;
}
__device__ __forceinline__ unsigned short f2b(float f) {
    union { float f; unsigned int u; } v; v.f = f;
    unsigned int u = v.u;
    unsigned int r = u + 0x7fffu + ((u >> 16) & 1u);   // RTNE
    return (unsigned short)(r >> 16);
}

// 5-bit Morton expansion: b4..b0 -> bits 12,9,6,3,0
__device__ __forceinline__ unsigned expand5(unsigned v) {
    v = (v | (v << 8)) & 0x100Fu;
    v = (v | (v << 4)) & 0x10C3u;
    v = (v | (v << 2)) & 0x1249u;
    return v;
}
__device__ __forceinline__ int vertex_cell(const float* __restrict__ verts, int i) {
    const float vx = verts[i * 3 + 0];
    const float vy = verts[i * 3 + 1];
    const float vz = verts[i * 3 + 2];
    int cx = (int)((vx + 1.0f) * 63.5f) >> 2;
    int cy = (int)((vy + 1.0f) * 63.5f) >> 2;
    int cz = (int)((vz + 1.0f) * 63.5f) >> 2;
    cx = min(max(cx, 0), 31); cy = min(max(cy, 0), 31); cz = min(max(cz, 0), 31);
    return (int)(expand5((unsigned)cx) | (expand5((unsigned)cy) << 1) | (expand5((unsigned)cz) << 2));
}

// ---- kernel 1 (v3): fp32 [C][D][H][W] -> bf16 [D][H][W][C] (FROZEN) ----
__global__ __launch_bounds__(256) void k_transpose(const float* __restrict__ vf,
                                                   unsigned short* __restrict__ vol) {
    const int t  = threadIdx.x;
    const int cq = t & 3;
    const int vo = blockIdx.x * 64 + (t >> 2);       // voxel id
    float v[8];
#pragma unroll
    for (int j = 0; j < 8; ++j) v[j] = vf[(size_t)(cq * 8 + j) * DHW + vo];
    union { uint4 u; unsigned short s[8]; } p;
#pragma unroll
    for (int j = 0; j < 8; ++j) p.s[j] = f2b(v[j]);
    ((uint4*)vol)[vo * 4 + cq] = p.u;
}

// ---- kernel 2a: Wd = w_d2@w_d1 (fp32 -> ws) + folded bias (FROZEN) ----
__global__ __launch_bounds__(1024) void k_fold1(
    const float* __restrict__ w_d1, const float* __restrict__ b_d1,
    const float* __restrict__ w_d2, const float* __restrict__ b_d2,
    const float* __restrict__ w_c1, const float* __restrict__ b_c1,
    const float* __restrict__ w_c2, const float* __restrict__ b_c2,
    const float* __restrict__ conv_w, const float* __restrict__ conv_b,
    float* __restrict__ WdG, float* __restrict__ biasOut)
{
    __shared__ float bd[32];
    const int t = threadIdx.x;
    const int o = t >> 5, cc = t & 31;
    float s1 = 0.f;
    for (int j = 0; j < 32; ++j) s1 += w_d2[o * 32 + j] * w_d1[j * 32 + cc];
    WdG[t] = s1;
    if (t < 32) {
        float s = b_d2[t];
        for (int j = 0; j < 32; ++j) s += w_d2[t * 32 + j] * b_d1[j];
        bd[t] = s;   // diff-branch bias after both layers
    }
    __syncthreads();
    if (t < 32) {    // t = o
        float ba = conv_b[t];
        for (int c = 0; c < 32; ++c) {
            float cs = 0.f;
            for (int k = 0; k < 27; ++k) cs += conv_w[(t * 32 + c) * 27 + k];
            ba += cs * bd[c];
        }
        float bc = b_c2[t];
        for (int j = 0; j < 32; ++j) bc += w_c2[t * 32 + j] * b_c1[j];
        biasOut[t] = ba + bc;
    }
}

// ---- kernel 2b: Et[o][k*32+cc] for one shift k per block (27 blocks) (FROZEN) ----
__global__ __launch_bounds__(1024) void k_fold2(
    const float* __restrict__ w_c1, const float* __restrict__ w_c2,
    const float* __restrict__ conv_w, const float* __restrict__ WdG,
    unsigned short* __restrict__ Et)
{
    const int k = blockIdx.x;
    __shared__ float WdL[1024];
    const int t = threadIdx.x;
    WdL[t] = WdG[t];
    __syncthreads();
    const int o = t >> 5, cc = t & 31;
    float s = 0.f;
    for (int c = 0; c < 32; ++c)
        s += conv_w[(o * 32 + c) * 27 + k] * WdL[c * 32 + cc];
    if (k == 13) {
        float wc = 0.f;
        for (int j = 0; j < 32; ++j) wc += w_c2[o * 32 + j] * w_c1[j * 32 + cc];
        float ms = 0.f;
        for (int c = 0; c < 32; ++c) {
            float cs = 0.f;
            for (int kk = 0; kk < 27; ++kk) cs += conv_w[(o * 32 + c) * 27 + kk];
            ms += cs * WdL[c * 32 + cc];
        }
        s += wc - ms;
    }
    Et[o * 864 + k * 32 + cc] = f2b(s);
}

// ---- sort kernels: Morton counting sort of vertices by 4^3-voxel cell ----
__global__ __launch_bounds__(256) void k_zero(int* __restrict__ hist) {
    hist[blockIdx.x * 256 + threadIdx.x] = 0;
}
__global__ __launch_bounds__(256) void k_hist(const float* __restrict__ verts,
                                              int* __restrict__ hist) {
    const int i = blockIdx.x * 256 + threadIdx.x;
    if (i < NVERT) atomicAdd(&hist[vertex_cell(verts, i)], 1);
}
__global__ __launch_bounds__(1024) void k_scan(const int* __restrict__ hist,
                                               int* __restrict__ ofs) {
    __shared__ int sm[1024];
    const int t = threadIdx.x;
    const int base = t * 32;
    int loc[32];
    int s = 0;
#pragma unroll
    for (int j = 0; j < 32; ++j) { loc[j] = hist[base + j]; s += loc[j]; }
    sm[t] = s;
    __syncthreads();
    for (int d = 1; d < 1024; d <<= 1) {
        int v = (t >= d) ? sm[t - d] : 0;
        __syncthreads();
        sm[t] += v;
        __syncthreads();
    }
    int run = sm[t] - s;        // exclusive prefix for this thread's 32 bins
#pragma unroll
    for (int j = 0; j < 32; ++j) { ofs[base + j] = run; run += loc[j]; }
}
__global__ __launch_bounds__(256) void k_scatter(const float* __restrict__ verts,
                                                 int* __restrict__ ofs,
                                                 int* __restrict__ perm) {
    const int i = blockIdx.x * 256 + threadIdx.x;
    if (i < NVERT) {
        const int pos = atomicAdd(&ofs[vertex_cell(verts, i)], 1);
        perm[pos] = i;
    }
}

// ---- kernel 3: fused trilinear sample + MFMA GEMM over SORTED vertices ----
// Wave pair covers 16 sorted positions; lane (m=lane&15, q=lane>>4) samples
// vertex perm[n0+m], channels [q*8,q*8+8) for shift kk == MFMA A-fragment.
// kk split 2-way across the pair for occupancy; bijective XCD-chunked block
// swizzle gives each XCD a contiguous Morton range (compact subvolume in L2).
__global__ __launch_bounds__(256) void k_fused(const float* __restrict__ verts,
                                               const unsigned short* __restrict__ vol,
                                               const unsigned short* __restrict__ Et,
                                               const float* __restrict__ bias,
                                               const int* __restrict__ perm,
                                               float* __restrict__ out) {
    __shared__ float part[2][64][8];                 // odd-wave partial accs (4 KB)
    // bijective XCD-chunked swizzle (nwg=1564, nwg%8=4 -> m204 variant)
    const int nwg = gridDim.x;
    const int xcd = blockIdx.x & 7, bix = blockIdx.x >> 3;
    const int qq = nwg >> 3, rr = nwg & 7;
    const int bid = (xcd < rr ? xcd * (qq + 1) : rr * (qq + 1) + (xcd - rr) * qq) + bix;

    const int wave = threadIdx.x >> 6, lane = threadIdx.x & 63;
    const int grp  = wave >> 1;                      // vertex group within block
    const int half = wave & 1;                       // kk half
    const int n0 = bid * 32 + grp * 16;
    const int m = lane & 15, q = lane >> 4;
    const int sp = min(n0 + m, NVERT - 1);           // sorted position
    const int nv = perm[sp];                         // real vertex id
    const float vx = verts[nv * 3 + 0];
    const float vy = verts[nv * 3 + 1];
    const float vz = verts[nv * 3 + 2];
    f32x4 acc0 = {0.f, 0.f, 0.f, 0.f}, acc1 = {0.f, 0.f, 0.f, 0.f};
    const uint4* v4 = (const uint4*)vol;
    const uint4* B0 = (const uint4*)(Et + m * 864) + q;
    const uint4* B1 = (const uint4*)(Et + (m + 16) * 864) + q;
    const int kk0 = half * 14;                       // 0 or 14
    const int kk1 = kk0 + 14 - half;                 // 14 or 27

    for (int kk = kk0; kk < kk1; ++kk) {
        const float sx = (float)(kk / 9) - 1.0f;
        const float sy = (float)((kk / 3) % 3) - 1.0f;
        const float sz = (float)(kk % 3) - 1.0f;
        float fx = (vx + sx * 0.0625f + 1.0f) * 63.5f;
        float fy = (vy + sy * 0.0625f + 1.0f) * 63.5f;
        float fz = (vz + sz * 0.0625f + 1.0f) * 63.5f;
        fx = fminf(fmaxf(fx, 0.f), 127.f);
        fy = fminf(fmaxf(fy, 0.f), 127.f);
        fz = fminf(fmaxf(fz, 0.f), 127.f);
        const int x0 = (int)floorf(fx); const float wx = fx - (float)x0; const int x1 = min(x0 + 1, 127);
        const int y0 = (int)floorf(fy); const float wy = fy - (float)y0; const int y1 = min(y0 + 1, 127);
        const int z0 = (int)floorf(fz); const float wz = fz - (float)z0; const int z1 = min(z0 + 1, 127);
        const float w0x = 1.f - wx, w0y = 1.f - wy, w0z = 1.f - wz;
        const float w000 = w0z * w0y * w0x, w001 = w0z * w0y * wx;
        const float w010 = w0z * wy * w0x,  w011 = w0z * wy * wx;
        const float w100 = wz * w0y * w0x,  w101 = wz * w0y * wx;
        const float w110 = wz * wy * w0x,   w111 = wz * wy * wx;

        const int zy00 = (z0 * 128 + y0) * 128, zy01 = (z0 * 128 + y1) * 128;
        const int zy10 = (z1 * 128 + y0) * 128, zy11 = (z1 * 128 + y1) * 128;
        union U4 { uint4 u; unsigned short s[8]; };
        U4 g000, g001, g010, g011, g100, g101, g110, g111;
        g000.u = v4[(zy00 + x0) * 4 + q];
        g001.u = v4[(zy00 + x1) * 4 + q];
        g010.u = v4[(zy01 + x0) * 4 + q];
        g011.u = v4[(zy01 + x1) * 4 + q];
        g100.u = v4[(zy10 + x0) * 4 + q];
        g101.u = v4[(zy10 + x1) * 4 + q];
        g110.u = v4[(zy11 + x0) * 4 + q];
        g111.u = v4[(zy11 + x1) * 4 + q];

        union AB { uint4 u; s16x8 v; unsigned short s[8]; };
        AB a, b0, b1;
        b0.u = B0[kk * 4];
        b1.u = B1[kk * 4];
#pragma unroll
        for (int j = 0; j < 8; ++j) {
            float s = bf2f(g000.s[j]) * w000 + bf2f(g001.s[j]) * w001
                    + bf2f(g010.s[j]) * w010 + bf2f(g011.s[j]) * w011
                    + bf2f(g100.s[j]) * w100 + bf2f(g101.s[j]) * w101
                    + bf2f(g110.s[j]) * w110 + bf2f(g111.s[j]) * w111;
            a.s[j] = f2b(s);                         // same RTNE as before
        }
        acc0 = __builtin_amdgcn_mfma_f32_16x16x32_bf16(a.v, b0.v, acc0, 0, 0, 0);
        acc1 = __builtin_amdgcn_mfma_f32_16x16x32_bf16(a.v, b1.v, acc1, 0, 0, 0);
    }

    if (half) {                                      // odd wave: publish partials
#pragma unroll
        for (int r = 0; r < 4; ++r) {
            part[grp][lane][r]     = acc0[r];
            part[grp][lane][4 + r] = acc1[r];
        }
    }
    __syncthreads();
    if (!half) {                                     // even wave: combine + store
        const float bi0 = bias[m], bi1 = bias[m + 16];
#pragma unroll
        for (int r = 0; r < 4; ++r) {
            const int n = n0 + q * 4 + r;            // sorted position of output row
            if (n < NVERT) {
                const int ov = perm[n];              // real vertex -> scatter store
                out[ov * 32 + m]      = acc0[r] + part[grp][lane][r]     + bi0;
                out[ov * 32 + 16 + m] = acc1[r] + part[grp][lane][4 + r] + bi1;
            }
        }
    }
}

extern "C" void kernel_launch(void* const* d_in, const int* in_sizes, int n_in,
                              void* d_out, int out_size, void* d_ws, size_t ws_size,
                              hipStream_t stream) {
    const float* vf     = (const float*)d_in[0];
    const float* verts  = (const float*)d_in[1];
    const float* w_d1   = (const float*)d_in[2];
    const float* b_d1   = (const float*)d_in[3];
    const float* w_d2   = (const float*)d_in[4];
    const float* b_d2   = (const float*)d_in[5];
    const float* w_c1   = (const float*)d_in[6];
    const float* b_c1   = (const float*)d_in[7];
    const float* w_c2   = (const float*)d_in[8];
    const float* b_c2   = (const float*)d_in[9];
    const float* conv_w = (const float*)d_in[10];
    const float* conv_b = (const float*)d_in[11];

    // ws: vol bf16 [DHW][32] | Et | bias | WdG | hist | ofs | perm
    char* ws = (char*)d_ws;
    unsigned short* vol   = (unsigned short*)ws;                                      // 134217728 B
    unsigned short* Et    = (unsigned short*)(ws + 134217728);                        // 55296 B
    float*          bias  = (float*)(ws + 134217728 + 55296);                         // 128 B
    float*          WdG   = (float*)(ws + 134217728 + 55296 + 128);                   // 4096 B
    int*            hist  = (int*)(ws + 134217728 + 55296 + 128 + 4096);              // 131072 B
    int*            ofs   = (int*)(ws + 134217728 + 55296 + 128 + 4096 + 131072);     // 131072 B
    int*            perm  = (int*)(ws + 134217728 + 55296 + 128 + 4096 + 262144);     // 200192 B

    k_transpose<<<DHW / 64, 256, 0, stream>>>(vf, vol);
    k_fold1<<<1, 1024, 0, stream>>>(w_d1, b_d1, w_d2, b_d2, w_c1, b_c1,
                                    w_c2, b_c2, conv_w, conv_b, WdG, bias);
    k_fold2<<<27, 1024, 0, stream>>>(w_c1, w_c2, conv_w, WdG, Et);
    k_zero<<<NCELL / 256, 256, 0, stream>>>(hist);
    k_hist<<<(NVERT + 255) / 256, 256, 0, stream>>>(verts, hist);
    k_scan<<<1, 1024, 0, stream>>>(hist, ofs);
    k_scatter<<<(NVERT + 255) / 256, 256, 0, stream>>>(verts, ofs, perm);
    k_fused<<<NPAD / 32, 256, 0, stream>>>(verts, vol, Et, bias, perm, (float*)d_out);
}

// Round 5
// 556.133 us; speedup vs baseline: 1.1150x; 1.0138x over previous
//
#include <hip/hip_runtime.h>
#include <hip/hip_bf16.h>

#define CH    32
#define DIM   128
#define DHW   (128*128*128)
#define NVERT 50000
#define NPAD  50048   /* 782 * 64 */
#define NCELL 32768   /* 32^3 Morton cells of 4^3 voxels */

typedef __attribute__((ext_vector_type(4))) float f32x4;
typedef __attribute__((ext_vector_type(8))) short s16x8;

__device__ __forceinline__ float bf2f(unsigned short h) {
    union { unsigned int u; float f; } v; v.u = ((unsigned int)h) << 16; return v.f;
}
__device__ __forceinline__ unsigned short f2b(float f) {
    union { float f; unsigned int u; } v; v.f = f;
    unsigned int u = v.u;
    unsigned int r = u + 0x7fffu + ((u >> 16) & 1u);   // RTNE
    return (unsigned short)(r >> 16);
}

// 5-bit Morton expansion: b4..b0 -> bits 12,9,6,3,0
__device__ __forceinline__ unsigned expand5(unsigned v) {
    v = (v | (v << 8)) & 0x100Fu;
    v = (v | (v << 4)) & 0x10C3u;
    v = (v | (v << 2)) & 0x1249u;
    return v;
}
__device__ __forceinline__ int vertex_cell(const float* __restrict__ verts, int i) {
    const float vx = verts[i * 3 + 0];
    const float vy = verts[i * 3 + 1];
    const float vz = verts[i * 3 + 2];
    int cx = (int)((vx + 1.0f) * 63.5f) >> 2;
    int cy = (int)((vy + 1.0f) * 63.5f) >> 2;
    int cz = (int)((vz + 1.0f) * 63.5f) >> 2;
    cx = min(max(cx, 0), 31); cy = min(max(cy, 0), 31); cz = min(max(cz, 0), 31);
    return (int)(expand5((unsigned)cx) | (expand5((unsigned)cy) << 1) | (expand5((unsigned)cz) << 2));
}

// ---- kernel 1 (v4): fp32 [C][D][H][W] -> bf16 [D][H][W][C] ----
// Thread = (voxel-group of 4, channel-quad cq). float4 loads (16 B/lane),
// bit-identical values/stores to v3 — pure instruction-count win.
__global__ __launch_bounds__(256) void k_transpose(const float* __restrict__ vf,
                                                   unsigned short* __restrict__ vol) {
    const int t  = threadIdx.x;
    const int cq = t & 3;
    const int vg = t >> 2;
    const int vo = blockIdx.x * 256 + vg * 4;        // first voxel of this thread
    union F4 { float4 q; float f[4]; } v[8];
#pragma unroll
    for (int j = 0; j < 8; ++j)
        v[j].q = *(const float4*)(vf + (size_t)(cq * 8 + j) * DHW + vo);
#pragma unroll
    for (int i = 0; i < 4; ++i) {
        union { uint4 u; unsigned short s[8]; } p;
#pragma unroll
        for (int j = 0; j < 8; ++j) p.s[j] = f2b(v[j].f[i]);
        ((uint4*)vol)[(vo + i) * 4 + cq] = p.u;
    }
}

// ---- kernel 2a: Wd = w_d2@w_d1 (fp32 -> ws) + folded bias (FROZEN) ----
__global__ __launch_bounds__(1024) void k_fold1(
    const float* __restrict__ w_d1, const float* __restrict__ b_d1,
    const float* __restrict__ w_d2, const float* __restrict__ b_d2,
    const float* __restrict__ w_c1, const float* __restrict__ b_c1,
    const float* __restrict__ w_c2, const float* __restrict__ b_c2,
    const float* __restrict__ conv_w, const float* __restrict__ conv_b,
    float* __restrict__ WdG, float* __restrict__ biasOut)
{
    __shared__ float bd[32];
    const int t = threadIdx.x;
    const int o = t >> 5, cc = t & 31;
    float s1 = 0.f;
    for (int j = 0; j < 32; ++j) s1 += w_d2[o * 32 + j] * w_d1[j * 32 + cc];
    WdG[t] = s1;
    if (t < 32) {
        float s = b_d2[t];
        for (int j = 0; j < 32; ++j) s += w_d2[t * 32 + j] * b_d1[j];
        bd[t] = s;   // diff-branch bias after both layers
    }
    __syncthreads();
    if (t < 32) {    // t = o
        float ba = conv_b[t];
        for (int c = 0; c < 32; ++c) {
            float cs = 0.f;
            for (int k = 0; k < 27; ++k) cs += conv_w[(t * 32 + c) * 27 + k];
            ba += cs * bd[c];
        }
        float bc = b_c2[t];
        for (int j = 0; j < 32; ++j) bc += w_c2[t * 32 + j] * b_c1[j];
        biasOut[t] = ba + bc;
    }
}

// ---- kernel 2b: Et[o][k*32+cc] for one shift k per block (27 blocks) (FROZEN) ----
__global__ __launch_bounds__(1024) void k_fold2(
    const float* __restrict__ w_c1, const float* __restrict__ w_c2,
    const float* __restrict__ conv_w, const float* __restrict__ WdG,
    unsigned short* __restrict__ Et)
{
    const int k = blockIdx.x;
    __shared__ float WdL[1024];
    const int t = threadIdx.x;
    WdL[t] = WdG[t];
    __syncthreads();
    const int o = t >> 5, cc = t & 31;
    float s = 0.f;
    for (int c = 0; c < 32; ++c)
        s += conv_w[(o * 32 + c) * 27 + k] * WdL[c * 32 + cc];
    if (k == 13) {
        float wc = 0.f;
        for (int j = 0; j < 32; ++j) wc += w_c2[o * 32 + j] * w_c1[j * 32 + cc];
        float ms = 0.f;
        for (int c = 0; c < 32; ++c) {
            float cs = 0.f;
            for (int kk = 0; kk < 27; ++kk) cs += conv_w[(o * 32 + c) * 27 + kk];
            ms += cs * WdL[c * 32 + cc];
        }
        s += wc - ms;
    }
    Et[o * 864 + k * 32 + cc] = f2b(s);
}

// ---- sort kernels: Morton counting sort of vertices by 4^3-voxel cell ----
__global__ __launch_bounds__(256) void k_zero(int* __restrict__ hist) {
    hist[blockIdx.x * 256 + threadIdx.x] = 0;
}
__global__ __launch_bounds__(256) void k_hist(const float* __restrict__ verts,
                                              int* __restrict__ hist) {
    const int i = blockIdx.x * 256 + threadIdx.x;
    if (i < NVERT) atomicAdd(&hist[vertex_cell(verts, i)], 1);
}
__global__ __launch_bounds__(1024) void k_scan(const int* __restrict__ hist,
                                               int* __restrict__ ofs) {
    __shared__ int sm[1024];
    const int t = threadIdx.x;
    const int base = t * 32;
    int loc[32];
    int s = 0;
#pragma unroll
    for (int j = 0; j < 32; ++j) { loc[j] = hist[base + j]; s += loc[j]; }
    sm[t] = s;
    __syncthreads();
    for (int d = 1; d < 1024; d <<= 1) {
        int v = (t >= d) ? sm[t - d] : 0;
        __syncthreads();
        sm[t] += v;
        __syncthreads();
    }
    int run = sm[t] - s;        // exclusive prefix for this thread's 32 bins
#pragma unroll
    for (int j = 0; j < 32; ++j) { ofs[base + j] = run; run += loc[j]; }
}
__global__ __launch_bounds__(256) void k_scatter(const float* __restrict__ verts,
                                                 int* __restrict__ ofs,
                                                 int* __restrict__ perm) {
    const int i = blockIdx.x * 256 + threadIdx.x;
    if (i < NVERT) {
        const int pos = atomicAdd(&ofs[vertex_cell(verts, i)], 1);
        perm[pos] = i;
    }
}

// ---- kernel 3: fused trilinear sample + MFMA GEMM over SORTED vertices ----
// EXACT R2 inner-loop body (numerics-proven: absmax 0.03125). Wave pair
// covers 16 sorted positions; kk split 14/13 across the pair; bijective
// XCD-chunked block swizzle for Morton-range L2 locality.
__global__ __launch_bounds__(256) void k_fused(const float* __restrict__ verts,
                                               const unsigned short* __restrict__ vol,
                                               const unsigned short* __restrict__ Et,
                                               const float* __restrict__ bias,
                                               const int* __restrict__ perm,
                                               float* __restrict__ out) {
    __shared__ float part[2][64][8];                 // odd-wave partial accs (4 KB)
    const int nwg = gridDim.x;
    const int xcd = blockIdx.x & 7, bix = blockIdx.x >> 3;
    const int qq = nwg >> 3, rr = nwg & 7;
    const int bid = (xcd < rr ? xcd * (qq + 1) : rr * (qq + 1) + (xcd - rr) * qq) + bix;

    const int wave = threadIdx.x >> 6, lane = threadIdx.x & 63;
    const int grp  = wave >> 1;                      // vertex group within block
    const int half = wave & 1;                       // kk half
    const int n0 = bid * 32 + grp * 16;
    const int m = lane & 15, q = lane >> 4;
    const int sp = min(n0 + m, NVERT - 1);           // sorted position
    const int nv = perm[sp];                         // real vertex id
    const float vx = verts[nv * 3 + 0];
    const float vy = verts[nv * 3 + 1];
    const float vz = verts[nv * 3 + 2];
    f32x4 acc0 = {0.f, 0.f, 0.f, 0.f}, acc1 = {0.f, 0.f, 0.f, 0.f};
    const uint4* v4 = (const uint4*)vol;
    const uint4* B0 = (const uint4*)(Et + m * 864) + q;
    const uint4* B1 = (const uint4*)(Et + (m + 16) * 864) + q;
    const int kk0 = half * 14;                       // 0 or 14
    const int kk1 = kk0 + 14 - half;                 // 14 or 27

    for (int kk = kk0; kk < kk1; ++kk) {
        const float sx = (float)(kk / 9) - 1.0f;
        const float sy = (float)((kk / 3) % 3) - 1.0f;
        const float sz = (float)(kk % 3) - 1.0f;
        float fx = (vx + sx * 0.0625f + 1.0f) * 63.5f;
        float fy = (vy + sy * 0.0625f + 1.0f) * 63.5f;
        float fz = (vz + sz * 0.0625f + 1.0f) * 63.5f;
        fx = fminf(fmaxf(fx, 0.f), 127.f);
        fy = fminf(fmaxf(fy, 0.f), 127.f);
        fz = fminf(fmaxf(fz, 0.f), 127.f);
        const int x0 = (int)floorf(fx); const float wx = fx - (float)x0; const int x1 = min(x0 + 1, 127);
        const int y0 = (int)floorf(fy); const float wy = fy - (float)y0; const int y1 = min(y0 + 1, 127);
        const int z0 = (int)floorf(fz); const float wz = fz - (float)z0; const int z1 = min(z0 + 1, 127);
        const float w0x = 1.f - wx, w0y = 1.f - wy, w0z = 1.f - wz;
        const float w000 = w0z * w0y * w0x, w001 = w0z * w0y * wx;
        const float w010 = w0z * wy * w0x,  w011 = w0z * wy * wx;
        const float w100 = wz * w0y * w0x,  w101 = wz * w0y * wx;
        const float w110 = wz * wy * w0x,   w111 = wz * wy * wx;

        const int zy00 = (z0 * 128 + y0) * 128, zy01 = (z0 * 128 + y1) * 128;
        const int zy10 = (z1 * 128 + y0) * 128, zy11 = (z1 * 128 + y1) * 128;
        union U4 { uint4 u; unsigned short s[8]; };
        U4 g000, g001, g010, g011, g100, g101, g110, g111;
        g000.u = v4[(zy00 + x0) * 4 + q];
        g001.u = v4[(zy00 + x1) * 4 + q];
        g010.u = v4[(zy01 + x0) * 4 + q];
        g011.u = v4[(zy01 + x1) * 4 + q];
        g100.u = v4[(zy10 + x0) * 4 + q];
        g101.u = v4[(zy10 + x1) * 4 + q];
        g110.u = v4[(zy11 + x0) * 4 + q];
        g111.u = v4[(zy11 + x1) * 4 + q];

        union AB { uint4 u; s16x8 v; unsigned short s[8]; };
        AB a, b0, b1;
        b0.u = B0[kk * 4];
        b1.u = B1[kk * 4];
#pragma unroll
        for (int j = 0; j < 8; ++j) {
            float s = bf2f(g000.s[j]) * w000 + bf2f(g001.s[j]) * w001
                    + bf2f(g010.s[j]) * w010 + bf2f(g011.s[j]) * w011
                    + bf2f(g100.s[j]) * w100 + bf2f(g101.s[j]) * w101
                    + bf2f(g110.s[j]) * w110 + bf2f(g111.s[j]) * w111;
            a.s[j] = f2b(s);                         // same RTNE as before
        }
        acc0 = __builtin_amdgcn_mfma_f32_16x16x32_bf16(a.v, b0.v, acc0, 0, 0, 0);
        acc1 = __builtin_amdgcn_mfma_f32_16x16x32_bf16(a.v, b1.v, acc1, 0, 0, 0);
    }

    if (half) {                                      // odd wave: publish partials
#pragma unroll
        for (int r = 0; r < 4; ++r) {
            part[grp][lane][r]     = acc0[r];
            part[grp][lane][4 + r] = acc1[r];
        }
    }
    __syncthreads();
    if (!half) {                                     // even wave: combine + store
        const float bi0 = bias[m], bi1 = bias[m + 16];
#pragma unroll
        for (int r = 0; r < 4; ++r) {
            const int n = n0 + q * 4 + r;            // sorted position of output row
            if (n < NVERT) {
                const int ov = perm[n];              // real vertex -> scatter store
                out[ov * 32 + m]      = acc0[r] + part[grp][lane][r]     + bi0;
                out[ov * 32 + 16 + m] = acc1[r] + part[grp][lane][4 + r] + bi1;
            }
        }
    }
}

extern "C" void kernel_launch(void* const* d_in, const int* in_sizes, int n_in,
                              void* d_out, int out_size, void* d_ws, size_t ws_size,
                              hipStream_t stream) {
    const float* vf     = (const float*)d_in[0];
    const float* verts  = (const float*)d_in[1];
    const float* w_d1   = (const float*)d_in[2];
    const float* b_d1   = (const float*)d_in[3];
    const float* w_d2   = (const float*)d_in[4];
    const float* b_d2   = (const float*)d_in[5];
    const float* w_c1   = (const float*)d_in[6];
    const float* b_c1   = (const float*)d_in[7];
    const float* w_c2   = (const float*)d_in[8];
    const float* b_c2   = (const float*)d_in[9];
    const float* conv_w = (const float*)d_in[10];
    const float* conv_b = (const float*)d_in[11];

    // ws: vol bf16 [DHW][32] | Et | bias | WdG | hist | ofs | perm
    char* ws = (char*)d_ws;
    unsigned short* vol   = (unsigned short*)ws;                                      // 134217728 B
    unsigned short* Et    = (unsigned short*)(ws + 134217728);                        // 55296 B
    float*          bias  = (float*)(ws + 134217728 + 55296);                         // 128 B
    float*          WdG   = (float*)(ws + 134217728 + 55296 + 128);                   // 4096 B
    int*            hist  = (int*)(ws + 134217728 + 55296 + 128 + 4096);              // 131072 B
    int*            ofs   = (int*)(ws + 134217728 + 55296 + 128 + 4096 + 131072);     // 131072 B
    int*            perm  = (int*)(ws + 134217728 + 55296 + 128 + 4096 + 262144);     // 200192 B

    k_transpose<<<DHW / 256, 256, 0, stream>>>(vf, vol);
    k_fold1<<<1, 1024, 0, stream>>>(w_d1, b_d1, w_d2, b_d2, w_c1, b_c1,
                                    w_c2, b_c2, conv_w, conv_b, WdG, bias);
    k_fold2<<<27, 1024, 0, stream>>>(w_c1, w_c2, conv_w, WdG, Et);
    k_zero<<<NCELL / 256, 256, 0, stream>>>(hist);
    k_hist<<<(NVERT + 255) / 256, 256, 0, stream>>>(verts, hist);
    k_scan<<<1, 1024, 0, stream>>>(hist, ofs);
    k_scatter<<<(NVERT + 255) / 256, 256, 0, stream>>>(verts, ofs, perm);
    k_fused<<<NPAD / 32, 256, 0, stream>>>(verts, vol, Et, bias, perm, (float*)d_out);
}